// Round 2
// baseline (3848.438 us; speedup 1.0000x reference)
//
#include <hip/hip_runtime.h>
#include <hip/hip_bf16.h>

#define EPSB 1e-5f

__device__ __forceinline__ float relu_aff(float a, float sc, float sh) {
    return fmaxf(fmaf(a, sc, sh), 0.0f);
}

// Fused Conv(5x5, pad2) + BN(inference) + ReLU + MaxPool(2x2) kernel.
// Each thread computes one pooled output pixel for TWO consecutive output
// channels. The 4 conv outputs under one pool window share a 6x6 input
// window -> 36 loads amortize 200 FMAs (2 channels).
template<int CI, int HIN, int WIN, int PH, int PW, bool SEG>
__global__ __launch_bounds__(256)
void conv_bn_pool(const float* __restrict__ in,
                  const float* __restrict__ wgt,   // (CO, CI, 5, 5)
                  const float* __restrict__ bias,
                  const float* __restrict__ g,
                  const float* __restrict__ be,
                  const float* __restrict__ m,
                  const float* __restrict__ v,
                  float* __restrict__ out,         // (N, CO, PH, PW)
                  int CO)
{
    const int n   = blockIdx.z;
    const int co0 = blockIdx.y * 2;
    const int idx = blockIdx.x * blockDim.x + threadIdx.x;
    if (idx >= PH * PW) return;
    const int ph = idx / PW, pw = idx % PW;

    const float sc0 = g[co0]     * rsqrtf(v[co0]     + EPSB);
    const float sh0 = fmaf(bias[co0]     - m[co0],     sc0, be[co0]);
    const float sc1 = g[co0 + 1] * rsqrtf(v[co0 + 1] + EPSB);
    const float sh1 = fmaf(bias[co0 + 1] - m[co0 + 1], sc1, be[co0 + 1]);

    float acc0[4] = {0.f, 0.f, 0.f, 0.f};
    float acc1[4] = {0.f, 0.f, 0.f, 0.f};
    const int h0  = 2 * ph - 2;   // top row of the shared 6x6 window
    const int w0c = 2 * pw - 2;   // left col

    size_t inbase; int rs;
    if (SEG) {
        // layer1 reads straight from x (16,1,100,4000): n = b*8 + l,
        // element (h,w) of segment = x[b*400000 + h*4000 + l*500 + w]
        const int b = n >> 3, l = n & 7;
        inbase = (size_t)b * 400000 + l * 500;
        rs = 4000;
    } else {
        inbase = (size_t)n * CI * HIN * WIN;
        rs = WIN;
    }

    const float* __restrict__ wp0 = wgt + (size_t)co0 * CI * 25;
    const float* __restrict__ wp1 = wp0 + CI * 25;

    for (int ci = 0; ci < CI; ++ci) {
        const float* __restrict__ ib = in + inbase + (size_t)ci * HIN * WIN;
        float win[6][6];
        #pragma unroll
        for (int r = 0; r < 6; ++r) {
            const int hh = h0 + r;
            const bool vr = (hh >= 0) & (hh < HIN);
            #pragma unroll
            for (int c = 0; c < 6; ++c) {
                const int ww = w0c + c;
                const bool ok = vr & (ww >= 0) & (ww < WIN);
                win[r][c] = ok ? ib[hh * rs + ww] : 0.0f;
            }
        }
        #pragma unroll
        for (int kh = 0; kh < 5; ++kh) {
            #pragma unroll
            for (int kw = 0; kw < 5; ++kw) {
                const float w0v = wp0[ci * 25 + kh * 5 + kw];
                const float w1v = wp1[ci * 25 + kh * 5 + kw];
                acc0[0] = fmaf(w0v, win[kh    ][kw    ], acc0[0]);
                acc0[1] = fmaf(w0v, win[kh    ][kw + 1], acc0[1]);
                acc0[2] = fmaf(w0v, win[kh + 1][kw    ], acc0[2]);
                acc0[3] = fmaf(w0v, win[kh + 1][kw + 1], acc0[3]);
                acc1[0] = fmaf(w1v, win[kh    ][kw    ], acc1[0]);
                acc1[1] = fmaf(w1v, win[kh    ][kw + 1], acc1[1]);
                acc1[2] = fmaf(w1v, win[kh + 1][kw    ], acc1[2]);
                acc1[3] = fmaf(w1v, win[kh + 1][kw + 1], acc1[3]);
            }
        }
    }

    // BN+ReLU applied per conv output, then max (correct even if scale<0)
    const float o0 = fmaxf(fmaxf(relu_aff(acc0[0], sc0, sh0), relu_aff(acc0[1], sc0, sh0)),
                           fmaxf(relu_aff(acc0[2], sc0, sh0), relu_aff(acc0[3], sc0, sh0)));
    const float o1 = fmaxf(fmaxf(relu_aff(acc1[0], sc1, sh1), relu_aff(acc1[1], sc1, sh1)),
                           fmaxf(relu_aff(acc1[2], sc1, sh1), relu_aff(acc1[3], sc1, sh1)));

    const size_t ob = ((size_t)n * CO + co0) * (size_t)(PH * PW) + idx;
    out[ob] = o0;
    out[ob + (size_t)(PH * PW)] = o1;
}

// h (128, 5952) @ fw1^T (5952, 32) + fb1 -> h1 (128, 32)
__global__ __launch_bounds__(64)
void fc1_kernel(const float* __restrict__ h,
                const float* __restrict__ fw1,
                const float* __restrict__ fb1,
                float* __restrict__ h1)
{
    const int n = blockIdx.x;
    const int j = blockIdx.y;
    const int lane = threadIdx.x;
    const float* hp = h   + (size_t)n * 5952;
    const float* wp = fw1 + (size_t)j * 5952;
    float s = 0.0f;
    for (int k = lane; k < 5952; k += 64) s = fmaf(hp[k], wp[k], s);
    #pragma unroll
    for (int off = 32; off > 0; off >>= 1) s += __shfl_down(s, off, 64);
    if (lane == 0) h1[n * 32 + j] = s + fb1[j];
}

// h1 (128,32) @ fw2^T (32,2) + fb2, then mean over 8 segments -> out (16,2)
__global__ __launch_bounds__(64)
void fc2_mean_kernel(const float* __restrict__ h1,
                     const float* __restrict__ fw2,
                     const float* __restrict__ fb2,
                     float* __restrict__ out)
{
    const int t = threadIdx.x;
    if (t >= 32) return;
    const int b = t >> 1, c = t & 1;
    float s = 0.0f;
    for (int l = 0; l < 8; ++l) {
        const float* hp = h1 + (size_t)(b * 8 + l) * 32;
        #pragma unroll
        for (int j = 0; j < 32; ++j) s = fmaf(hp[j], fw2[c * 32 + j], s);
    }
    out[t] = fmaf(s, 0.125f, fb2[c]);
}

extern "C" void kernel_launch(void* const* d_in, const int* in_sizes, int n_in,
                              void* d_out, int out_size, void* d_ws, size_t ws_size,
                              hipStream_t stream)
{
    const float* x   = (const float*)d_in[0];
    const float* w1  = (const float*)d_in[1];
    const float* b1  = (const float*)d_in[2];
    const float* g1  = (const float*)d_in[3];
    const float* be1 = (const float*)d_in[4];
    const float* m1  = (const float*)d_in[5];
    const float* v1  = (const float*)d_in[6];
    const float* w2  = (const float*)d_in[7];
    const float* b2  = (const float*)d_in[8];
    const float* g2  = (const float*)d_in[9];
    const float* be2 = (const float*)d_in[10];
    const float* m2  = (const float*)d_in[11];
    const float* v2  = (const float*)d_in[12];
    const float* w3  = (const float*)d_in[13];
    const float* b3  = (const float*)d_in[14];
    const float* g3  = (const float*)d_in[15];
    const float* be3 = (const float*)d_in[16];
    const float* m3  = (const float*)d_in[17];
    const float* v3  = (const float*)d_in[18];
    const float* w4  = (const float*)d_in[19];
    const float* b4  = (const float*)d_in[20];
    const float* g4  = (const float*)d_in[21];
    const float* be4 = (const float*)d_in[22];
    const float* m4  = (const float*)d_in[23];
    const float* v4  = (const float*)d_in[24];
    const float* fw1 = (const float*)d_in[25];
    const float* fb1 = (const float*)d_in[26];
    const float* fw2 = (const float*)d_in[27];
    const float* fb2 = (const float*)d_in[28];

    char* ws = (char*)d_ws;
    // region A (102.4 MB): l1, later reused for l3
    // region B (51.2 MB @ +102.4MB): l2, later reused for l4
    float* l1 = (float*)(ws);                     // 128*16*50*250 = 25.6M f32
    float* l2 = (float*)(ws + 102400000);         // 128*32*25*125 = 12.8M f32
    float* l3 = (float*)(ws);                     // 128*64*12*62  =  6.1M f32
    float* l4 = (float*)(ws + 102400000);         // 128*32*6*31   = 762K f32
    float* h1 = (float*)(ws + 153600000);         // 128*32 f32

    const dim3 blk(256);
    conv_bn_pool<1, 100, 500, 50, 250, true>
        <<<dim3((50 * 250 + 255) / 256, 8, 128), blk, 0, stream>>>(
            x, w1, b1, g1, be1, m1, v1, l1, 16);
    conv_bn_pool<16, 50, 250, 25, 125, false>
        <<<dim3((25 * 125 + 255) / 256, 16, 128), blk, 0, stream>>>(
            l1, w2, b2, g2, be2, m2, v2, l2, 32);
    conv_bn_pool<32, 25, 125, 12, 62, false>
        <<<dim3((12 * 62 + 255) / 256, 32, 128), blk, 0, stream>>>(
            l2, w3, b3, g3, be3, m3, v3, l3, 64);
    conv_bn_pool<64, 12, 62, 6, 31, false>
        <<<dim3(1, 16, 128), blk, 0, stream>>>(
            l3, w4, b4, g4, be4, m4, v4, l4, 32);
    fc1_kernel<<<dim3(128, 32), 64, 0, stream>>>(l4, fw1, fb1, h1);
    fc2_mean_kernel<<<1, 64, 0, stream>>>(h1, fw2, fb2, (float*)d_out);
}

// Round 3
// 630.171 us; speedup vs baseline: 6.1070x; 6.1070x over previous
//
#include <hip/hip_runtime.h>
#include <hip/hip_bf16.h>

#define EPSB 1e-5f

typedef short s16x8 __attribute__((ext_vector_type(8)));
typedef float f32x16 __attribute__((ext_vector_type(16)));

// ---------------- workspace layout (bytes) ----------------
// padded NHWC bf16 activation buffers (zeroed by one memset each call):
//  p1: 128 x [54][260][16]  = 57,507,840 B   (conv1 out / conv2 in)
//  p2: 128 x [29][136][32]  = 32,309,248 B   (conv2 out / conv3 in)
//  p3: 128 x [16][68][64]   = 17,825,792 B   (conv3 out / conv4 in)
#define P1_OFF   0
#define P2_OFF   57507840
#define P3_OFF   89817088
#define PTOT     107642880
#define L4_OFF   107642880   // 128x32x6x31 f32 NCHW = 3,047,424 B
#define H1_OFF   110690304   // 128x32 f32
#define WT2_OFF  110706688   // [25][32][16] bf16
#define WT3_OFF  110732288   // [25][64][32] bf16
#define WT4_OFF  110834688   // [25][32][64] bf16
#define SS2_OFF  110937088   // 2*32 f32 (scale, shift)
#define SS3_OFF  110937344   // 2*64 f32
#define SS4_OFF  110937856   // 2*32 f32

// Reorder conv weights (CO,CI,5,5) f32 -> [tap=kh*5+kw][CO][CI] bf16
__global__ __launch_bounds__(256)
void wtrans_kernel(const float* __restrict__ src, __hip_bfloat16* __restrict__ dst,
                   int CO, int CI)
{
    const int idx = blockIdx.x * 256 + threadIdx.x;
    if (idx >= CO * CI * 25) return;
    const int co  = idx / (CI * 25);
    const int rem = idx % (CI * 25);
    const int ci  = rem / 25;
    const int tap = rem % 25;
    dst[((size_t)tap * CO + co) * CI + ci] = __float2bfloat16(src[idx]);
}

// Per-channel BN fold: out[0..CO)=scale, out[CO..2CO)=shift
__global__ __launch_bounds__(64)
void scsh_kernel(const float* __restrict__ b, const float* __restrict__ g,
                 const float* __restrict__ be, const float* __restrict__ m,
                 const float* __restrict__ v, float* __restrict__ out, int CO)
{
    const int i = threadIdx.x;
    if (i < CO) {
        const float sc = g[i] * rsqrtf(v[i] + EPSB);
        out[i]      = sc;
        out[CO + i] = fmaf(b[i] - m[i], sc, be[i]);
    }
}

// conv1: CI=1, fp32 direct (input read straight from x), fused BN+ReLU+pool,
// writes padded NHWC bf16 p1: per-n [54][260][16], interior at [2+ph][2+pw].
__global__ __launch_bounds__(256)
void conv1_kernel(const float* __restrict__ x,
                  const float* __restrict__ wgt,   // (16,1,5,5)
                  const float* __restrict__ bias,
                  const float* __restrict__ g,
                  const float* __restrict__ be,
                  const float* __restrict__ m,
                  const float* __restrict__ v,
                  __hip_bfloat16* __restrict__ p1)
{
    const int n   = blockIdx.z;            // 0..127 (b*8 + l)
    const int co0 = blockIdx.y * 2;
    const int idx = blockIdx.x * 256 + threadIdx.x;
    if (idx >= 50 * 250) return;
    const int ph = idx / 250, pw = idx % 250;

    const float sc0 = g[co0]     * rsqrtf(v[co0]     + EPSB);
    const float sh0 = fmaf(bias[co0]     - m[co0],     sc0, be[co0]);
    const float sc1 = g[co0 + 1] * rsqrtf(v[co0 + 1] + EPSB);
    const float sh1 = fmaf(bias[co0 + 1] - m[co0 + 1], sc1, be[co0 + 1]);

    const int b = n >> 3, l = n & 7;
    const float* ib = x + (size_t)b * 400000 + l * 500;

    const int h0  = 2 * ph - 2;
    const int w0c = 2 * pw - 2;
    float win[6][6];
    #pragma unroll
    for (int r = 0; r < 6; ++r) {
        const int hh = h0 + r;
        const bool vr = (hh >= 0) & (hh < 100);
        #pragma unroll
        for (int c = 0; c < 6; ++c) {
            const int ww = w0c + c;
            const bool ok = vr & (ww >= 0) & (ww < 500);
            win[r][c] = ok ? ib[hh * 4000 + ww] : 0.0f;
        }
    }
    float acc0[4] = {0.f,0.f,0.f,0.f}, acc1[4] = {0.f,0.f,0.f,0.f};
    #pragma unroll
    for (int kh = 0; kh < 5; ++kh) {
        #pragma unroll
        for (int kw = 0; kw < 5; ++kw) {
            const float w0v = wgt[co0 * 25 + kh * 5 + kw];
            const float w1v = wgt[(co0 + 1) * 25 + kh * 5 + kw];
            acc0[0] = fmaf(w0v, win[kh  ][kw  ], acc0[0]);
            acc0[1] = fmaf(w0v, win[kh  ][kw+1], acc0[1]);
            acc0[2] = fmaf(w0v, win[kh+1][kw  ], acc0[2]);
            acc0[3] = fmaf(w0v, win[kh+1][kw+1], acc0[3]);
            acc1[0] = fmaf(w1v, win[kh  ][kw  ], acc1[0]);
            acc1[1] = fmaf(w1v, win[kh  ][kw+1], acc1[1]);
            acc1[2] = fmaf(w1v, win[kh+1][kw  ], acc1[2]);
            acc1[3] = fmaf(w1v, win[kh+1][kw+1], acc1[3]);
        }
    }
    #define RA(a, s, h) fmaxf(fmaf((a), (s), (h)), 0.0f)
    const float o0 = fmaxf(fmaxf(RA(acc0[0],sc0,sh0), RA(acc0[1],sc0,sh0)),
                           fmaxf(RA(acc0[2],sc0,sh0), RA(acc0[3],sc0,sh0)));
    const float o1 = fmaxf(fmaxf(RA(acc1[0],sc1,sh1), RA(acc1[1],sc1,sh1)),
                           fmaxf(RA(acc1[2],sc1,sh1), RA(acc1[3],sc1,sh1)));
    #undef RA
    const size_t ob = (size_t)n * (54 * 260 * 16) + ((2 + ph) * 260 + (2 + pw)) * 16 + co0;
    p1[ob]     = __float2bfloat16(o0);
    p1[ob + 1] = __float2bfloat16(o1);
}

// Generic MFMA conv+BN+ReLU+pool.
// Input: padded NHWC bf16, per-n [HINP][WINP][CI], interior origin at (2,2).
// Weights: [25][CO][CI] bf16.  scsh: [2][CO] f32.
// Each wave computes a 32co x 32w tile for conv rows (2r, 2r+1), pools to
// 16co... (32 co rows) x 16 pooled cols, stores bf16 padded NHWC (or f32 NCHW).
template<int CI, int CO, int HINP, int WINP, int HOUTP, int WOUTP,
         int PH, int PW, int NT, int NCOT, bool NCHW_OUT>
__global__ __launch_bounds__(256)
void conv_mfma(const __hip_bfloat16* __restrict__ pin,
               const __hip_bfloat16* __restrict__ wq,
               const float* __restrict__ scsh,
               void* __restrict__ pout)
{
    const int lane = threadIdx.x & 63;
    int t = blockIdx.x * 4 + (threadIdx.x >> 6);
    const int cot = t % NCOT; t /= NCOT;
    const int wt  = t % NT;   t /= NT;
    const int r   = t % PH;   t /= PH;
    const int n   = t;
    if (n >= 128) return;

    const int lw = lane & 31, loct = lane >> 5;
    const int co0 = cot * 32;
    const int w0  = wt * 32;

    const __hip_bfloat16* bbase = pin + (size_t)n * (HINP * WINP * CI)
                                + ((2 * r) * WINP + w0 + lw) * CI + loct * 8;
    const __hip_bfloat16* abase = wq + (co0 + lw) * CI + loct * 8;

    f32x16 acc0 = {};
    f32x16 acc1 = {};

    #pragma unroll
    for (int kw = 0; kw < 5; ++kw) {
        #pragma unroll
        for (int s = 0; s < CI / 16; ++s) {
            s16x8 bfr[6];
            #pragma unroll
            for (int j = 0; j < 6; ++j)
                bfr[j] = *reinterpret_cast<const s16x8*>(bbase + (j * WINP + kw) * CI + s * 16);
            #pragma unroll
            for (int kh = 0; kh < 5; ++kh) {
                const s16x8 a = *reinterpret_cast<const s16x8*>(
                    abase + (size_t)((kh * 5 + kw) * CO) * CI + s * 16);
                acc0 = __builtin_amdgcn_mfma_f32_32x32x16_bf16(a, bfr[kh],     acc0, 0, 0, 0);
                acc1 = __builtin_amdgcn_mfma_f32_32x32x16_bf16(a, bfr[kh + 1], acc1, 0, 0, 0);
            }
        }
    }

    // epilogue: BN+ReLU per conv output, pool rows (acc0,acc1) and col pairs
    const int pw = wt * 16 + (lw >> 1);
    const bool act = ((lane & 1) == 0) && (pw < PW);
    #pragma unroll
    for (int reg = 0; reg < 16; ++reg) {
        const int co = co0 + (reg & 3) + 8 * (reg >> 2) + 4 * loct;
        const float sc = scsh[co], sh = scsh[CO + co];
        const float v0 = fmaxf(fmaf(acc0[reg], sc, sh), 0.0f);
        const float v1 = fmaxf(fmaf(acc1[reg], sc, sh), 0.0f);
        float vm = fmaxf(v0, v1);
        vm = fmaxf(vm, __shfl_xor(vm, 1, 64));
        if (act) {
            if (NCHW_OUT) {
                ((float*)pout)[(((size_t)n * CO + co) * PH + r) * PW + pw] = vm;
            } else {
                ((__hip_bfloat16*)pout)[(size_t)n * (HOUTP * WOUTP * CO)
                    + ((2 + r) * WOUTP + (2 + pw)) * CO + co] = __float2bfloat16(vm);
            }
        }
    }
}

// h (128, 5952 NCHW f32) @ fw1^T + fb1 -> h1 (128,32)
__global__ __launch_bounds__(64)
void fc1_kernel(const float* __restrict__ h,
                const float* __restrict__ fw1,
                const float* __restrict__ fb1,
                float* __restrict__ h1)
{
    const int n = blockIdx.x;
    const int j = blockIdx.y;
    const int lane = threadIdx.x;
    const float* hp = h   + (size_t)n * 5952;
    const float* wp = fw1 + (size_t)j * 5952;
    float s = 0.0f;
    for (int k = lane; k < 5952; k += 64) s = fmaf(hp[k], wp[k], s);
    #pragma unroll
    for (int off = 32; off > 0; off >>= 1) s += __shfl_down(s, off, 64);
    if (lane == 0) h1[n * 32 + j] = s + fb1[j];
}

__global__ __launch_bounds__(64)
void fc2_mean_kernel(const float* __restrict__ h1,
                     const float* __restrict__ fw2,
                     const float* __restrict__ fb2,
                     float* __restrict__ out)
{
    const int t = threadIdx.x;
    if (t >= 32) return;
    const int b = t >> 1, c = t & 1;
    float s = 0.0f;
    for (int l = 0; l < 8; ++l) {
        const float* hp = h1 + (size_t)(b * 8 + l) * 32;
        #pragma unroll
        for (int j = 0; j < 32; ++j) s = fmaf(hp[j], fw2[c * 32 + j], s);
    }
    out[t] = fmaf(s, 0.125f, fb2[c]);
}

extern "C" void kernel_launch(void* const* d_in, const int* in_sizes, int n_in,
                              void* d_out, int out_size, void* d_ws, size_t ws_size,
                              hipStream_t stream)
{
    const float* x   = (const float*)d_in[0];
    const float* w1  = (const float*)d_in[1];
    const float* b1  = (const float*)d_in[2];
    const float* g1  = (const float*)d_in[3];
    const float* be1 = (const float*)d_in[4];
    const float* m1  = (const float*)d_in[5];
    const float* v1  = (const float*)d_in[6];
    const float* w2  = (const float*)d_in[7];
    const float* b2  = (const float*)d_in[8];
    const float* g2  = (const float*)d_in[9];
    const float* be2 = (const float*)d_in[10];
    const float* m2  = (const float*)d_in[11];
    const float* v2  = (const float*)d_in[12];
    const float* w3  = (const float*)d_in[13];
    const float* b3  = (const float*)d_in[14];
    const float* g3  = (const float*)d_in[15];
    const float* be3 = (const float*)d_in[16];
    const float* m3  = (const float*)d_in[17];
    const float* v3  = (const float*)d_in[18];
    const float* w4  = (const float*)d_in[19];
    const float* b4  = (const float*)d_in[20];
    const float* g4  = (const float*)d_in[21];
    const float* be4 = (const float*)d_in[22];
    const float* m4  = (const float*)d_in[23];
    const float* v4  = (const float*)d_in[24];
    const float* fw1 = (const float*)d_in[25];
    const float* fb1 = (const float*)d_in[26];
    const float* fw2 = (const float*)d_in[27];
    const float* fb2 = (const float*)d_in[28];

    char* ws = (char*)d_ws;
    __hip_bfloat16* p1  = (__hip_bfloat16*)(ws + P1_OFF);
    __hip_bfloat16* p2  = (__hip_bfloat16*)(ws + P2_OFF);
    __hip_bfloat16* p3  = (__hip_bfloat16*)(ws + P3_OFF);
    float*          l4  = (float*)(ws + L4_OFF);
    float*          h1  = (float*)(ws + H1_OFF);
    __hip_bfloat16* wt2 = (__hip_bfloat16*)(ws + WT2_OFF);
    __hip_bfloat16* wt3 = (__hip_bfloat16*)(ws + WT3_OFF);
    __hip_bfloat16* wt4 = (__hip_bfloat16*)(ws + WT4_OFF);
    float*          ss2 = (float*)(ws + SS2_OFF);
    float*          ss3 = (float*)(ws + SS3_OFF);
    float*          ss4 = (float*)(ws + SS4_OFF);

    // zero padded activation buffers (halos must be 0 every call)
    hipMemsetAsync(ws, 0, PTOT, stream);

    wtrans_kernel<<<dim3(50),  256, 0, stream>>>(w2, wt2, 32, 16);
    wtrans_kernel<<<dim3(200), 256, 0, stream>>>(w3, wt3, 64, 32);
    wtrans_kernel<<<dim3(200), 256, 0, stream>>>(w4, wt4, 32, 64);
    scsh_kernel<<<1, 64, 0, stream>>>(b2, g2, be2, m2, v2, ss2, 32);
    scsh_kernel<<<1, 64, 0, stream>>>(b3, g3, be3, m3, v3, ss3, 64);
    scsh_kernel<<<1, 64, 0, stream>>>(b4, g4, be4, m4, v4, ss4, 32);

    conv1_kernel<<<dim3(49, 8, 128), 256, 0, stream>>>(x, w1, b1, g1, be1, m1, v1, p1);

    // conv2: CI=16 CO=32 in [54][260][16] out [29][136][32], PH=25 PW=125, 8 w-tiles
    conv_mfma<16, 32, 54, 260, 29, 136, 25, 125, 8, 1, false>
        <<<dim3(128 * 25 * 8 / 4), 256, 0, stream>>>(p1, wt2, ss2, p2);
    // conv3: CI=32 CO=64 in [29][136][32] out [16][68][64], PH=12 PW=62, 4 w-tiles, 2 co-tiles
    conv_mfma<32, 64, 29, 136, 16, 68, 12, 62, 4, 2, false>
        <<<dim3(128 * 12 * 4 * 2 / 4), 256, 0, stream>>>(p2, wt3, ss3, p3);
    // conv4: CI=64 CO=32 in [16][68][64], PH=6 PW=31, 2 w-tiles, NCHW f32 out
    conv_mfma<64, 32, 16, 68, 0, 0, 6, 31, 2, 1, true>
        <<<dim3(128 * 6 * 2 / 4), 256, 0, stream>>>(p3, wt4, ss4, l4);

    fc1_kernel<<<dim3(128, 32), 64, 0, stream>>>(l4, fw1, fb1, h1);
    fc2_mean_kernel<<<1, 64, 0, stream>>>(h1, fw2, fb2, (float*)d_out);
}

// Round 4
// 501.427 us; speedup vs baseline: 7.6750x; 1.2568x over previous
//
#include <hip/hip_runtime.h>
#include <hip/hip_bf16.h>

#define EPSB 1e-5f

typedef short s16x8 __attribute__((ext_vector_type(8)));
typedef float f32x16 __attribute__((ext_vector_type(16)));

// ---------------- workspace layout (bytes) ----------------
//  p1: 128 x [54][260][16]  = 57,507,840 B   (conv1 out / conv2 in)
//  p2: 128 x [29][136][32]  = 32,309,248 B   (conv2 out / conv3 in)
//  p3: 128 x [16][68][64]   = 17,825,792 B   (conv3 out / conv4 in)
#define P1_OFF   0
#define P2_OFF   57507840
#define P3_OFF   89817088
#define PTOT     107642880
#define L4_OFF   107642880   // 128x32x6x31 f32 NCHW = 3,047,424 B
#define H1_OFF   110690304   // 128x32 f32
#define WT2_OFF  110706688   // [25][32][16] bf16
#define WT3_OFF  110732288   // [25][64][32] bf16
#define WT4_OFF  110834688   // [25][32][64] bf16
#define SS2_OFF  110937088   // 2*32 f32 (scale, shift)
#define SS3_OFF  110937344   // 2*64 f32
#define SS4_OFF  110937856   // 2*32 f32

__device__ __forceinline__ unsigned short bf16bits(float f) {
    __hip_bfloat16 h = __float2bfloat16(f);
    union { __hip_bfloat16 h; unsigned short u; } cv; cv.h = h; return cv.u;
}

// Zero only the pad/halo elements of a padded NHWC buffer (poisoned 0xAA
// each call). Interior rows [2,2+IH), cols [2,2+IW) are skipped (conv
// kernels overwrite them fully).
template<int HP, int WP, int C, int IH, int IW>
__global__ __launch_bounds__(256)
void pad_zero(__hip_bfloat16* __restrict__ buf)
{
    const int idx = blockIdx.x * 256 + threadIdx.x;
    if (idx >= 128 * HP * WP) return;
    const int rc = idx % (HP * WP);
    const int row = rc / WP, col = rc % WP;
    const bool pad = (row < 2) | (row >= 2 + IH) | (col < 2) | (col >= 2 + IW);
    if (!pad) return;
    int4* p = reinterpret_cast<int4*>(buf + (size_t)idx * C);
    #pragma unroll
    for (int i = 0; i < C * 2 / 16; ++i) p[i] = int4{0, 0, 0, 0};
}

// Reorder conv weights (CO,CI,5,5) f32 -> [tap=kh*5+kw][CO][CI] bf16
__global__ __launch_bounds__(256)
void wtrans_kernel(const float* __restrict__ src, __hip_bfloat16* __restrict__ dst,
                   int CO, int CI)
{
    const int idx = blockIdx.x * 256 + threadIdx.x;
    if (idx >= CO * CI * 25) return;
    const int co  = idx / (CI * 25);
    const int rem = idx % (CI * 25);
    const int ci  = rem / 25;
    const int tap = rem % 25;
    dst[((size_t)tap * CO + co) * CI + ci] = __float2bfloat16(src[idx]);
}

// Per-channel BN fold: out[0..CO)=scale, out[CO..2CO)=shift
__global__ __launch_bounds__(64)
void scsh_kernel(const float* __restrict__ b, const float* __restrict__ g,
                 const float* __restrict__ be, const float* __restrict__ m,
                 const float* __restrict__ v, float* __restrict__ out, int CO)
{
    const int i = threadIdx.x;
    if (i < CO) {
        const float sc = g[i] * rsqrtf(v[i] + EPSB);
        out[i]      = sc;
        out[CO + i] = fmaf(b[i] - m[i], sc, be[i]);
    }
}

// conv1: CI=1, fp32 direct. One thread = one pooled pixel, ALL 16 output
// channels: 36-element window loaded ONCE, one 32B coalesced store.
__global__ __launch_bounds__(256)
void conv1_kernel(const float* __restrict__ x,
                  const float* __restrict__ wgt,   // (16,1,5,5)
                  const float* __restrict__ bias,
                  const float* __restrict__ g,
                  const float* __restrict__ be,
                  const float* __restrict__ m,
                  const float* __restrict__ v,
                  __hip_bfloat16* __restrict__ p1)
{
    const int n   = blockIdx.y;            // 0..127 (b*8 + l)
    const int idx = blockIdx.x * 256 + threadIdx.x;
    if (idx >= 50 * 250) return;
    const int ph = idx / 250, pw = idx % 250;

    const int b = n >> 3, l = n & 7;
    const float* ib = x + (size_t)b * 400000 + l * 500;

    const int h0  = 2 * ph - 2;
    const int w0c = 2 * pw - 2;
    float win[6][6];
    #pragma unroll
    for (int r = 0; r < 6; ++r) {
        const int hh = h0 + r;
        const bool vr = (hh >= 0) & (hh < 100);
        #pragma unroll
        for (int c = 0; c < 6; ++c) {
            const int ww = w0c + c;
            const bool ok = vr & (ww >= 0) & (ww < 500);
            win[r][c] = ok ? ib[hh * 4000 + ww] : 0.0f;
        }
    }

    float o[16];
    #pragma unroll
    for (int co = 0; co < 16; ++co) {
        float a0 = 0.f, a1 = 0.f, a2 = 0.f, a3 = 0.f;
        #pragma unroll
        for (int kh = 0; kh < 5; ++kh) {
            #pragma unroll
            for (int kw = 0; kw < 5; ++kw) {
                const float w = wgt[co * 25 + kh * 5 + kw];
                a0 = fmaf(w, win[kh  ][kw  ], a0);
                a1 = fmaf(w, win[kh  ][kw+1], a1);
                a2 = fmaf(w, win[kh+1][kw  ], a2);
                a3 = fmaf(w, win[kh+1][kw+1], a3);
            }
        }
        const float sc = g[co] * rsqrtf(v[co] + EPSB);
        const float sh = fmaf(bias[co] - m[co], sc, be[co]);
        #define RA(a) fmaxf(fmaf((a), sc, sh), 0.0f)
        o[co] = fmaxf(fmaxf(RA(a0), RA(a1)), fmaxf(RA(a2), RA(a3)));
        #undef RA
    }

    int4 v0, v1;
    v0.x = bf16bits(o[0])  | (bf16bits(o[1])  << 16);
    v0.y = bf16bits(o[2])  | (bf16bits(o[3])  << 16);
    v0.z = bf16bits(o[4])  | (bf16bits(o[5])  << 16);
    v0.w = bf16bits(o[6])  | (bf16bits(o[7])  << 16);
    v1.x = bf16bits(o[8])  | (bf16bits(o[9])  << 16);
    v1.y = bf16bits(o[10]) | (bf16bits(o[11]) << 16);
    v1.z = bf16bits(o[12]) | (bf16bits(o[13]) << 16);
    v1.w = bf16bits(o[14]) | (bf16bits(o[15]) << 16);
    int4* dst = reinterpret_cast<int4*>(
        p1 + (size_t)n * (54 * 260 * 16) + ((2 + ph) * 260 + (2 + pw)) * 16);
    dst[0] = v0;
    dst[1] = v1;
}

// Generic MFMA conv+BN+ReLU+pool (unchanged from round 2).
template<int CI, int CO, int HINP, int WINP, int HOUTP, int WOUTP,
         int PH, int PW, int NT, int NCOT, bool NCHW_OUT>
__global__ __launch_bounds__(256)
void conv_mfma(const __hip_bfloat16* __restrict__ pin,
               const __hip_bfloat16* __restrict__ wq,
               const float* __restrict__ scsh,
               void* __restrict__ pout)
{
    const int lane = threadIdx.x & 63;
    int t = blockIdx.x * 4 + (threadIdx.x >> 6);
    const int cot = t % NCOT; t /= NCOT;
    const int wt  = t % NT;   t /= NT;
    const int r   = t % PH;   t /= PH;
    const int n   = t;
    if (n >= 128) return;

    const int lw = lane & 31, loct = lane >> 5;
    const int co0 = cot * 32;
    const int w0  = wt * 32;

    const __hip_bfloat16* bbase = pin + (size_t)n * (HINP * WINP * CI)
                                + ((2 * r) * WINP + w0 + lw) * CI + loct * 8;
    const __hip_bfloat16* abase = wq + (co0 + lw) * CI + loct * 8;

    f32x16 acc0 = {};
    f32x16 acc1 = {};

    #pragma unroll
    for (int kw = 0; kw < 5; ++kw) {
        #pragma unroll
        for (int s = 0; s < CI / 16; ++s) {
            s16x8 bfr[6];
            #pragma unroll
            for (int j = 0; j < 6; ++j)
                bfr[j] = *reinterpret_cast<const s16x8*>(bbase + (j * WINP + kw) * CI + s * 16);
            #pragma unroll
            for (int kh = 0; kh < 5; ++kh) {
                const s16x8 a = *reinterpret_cast<const s16x8*>(
                    abase + (size_t)((kh * 5 + kw) * CO) * CI + s * 16);
                acc0 = __builtin_amdgcn_mfma_f32_32x32x16_bf16(a, bfr[kh],     acc0, 0, 0, 0);
                acc1 = __builtin_amdgcn_mfma_f32_32x32x16_bf16(a, bfr[kh + 1], acc1, 0, 0, 0);
            }
        }
    }

    const int pw = wt * 16 + (lw >> 1);
    const bool act = ((lane & 1) == 0) && (pw < PW);
    #pragma unroll
    for (int reg = 0; reg < 16; ++reg) {
        const int co = co0 + (reg & 3) + 8 * (reg >> 2) + 4 * loct;
        const float sc = scsh[co], sh = scsh[CO + co];
        const float v0 = fmaxf(fmaf(acc0[reg], sc, sh), 0.0f);
        const float v1 = fmaxf(fmaf(acc1[reg], sc, sh), 0.0f);
        float vm = fmaxf(v0, v1);
        vm = fmaxf(vm, __shfl_xor(vm, 1, 64));
        if (act) {
            if (NCHW_OUT) {
                ((float*)pout)[(((size_t)n * CO + co) * PH + r) * PW + pw] = vm;
            } else {
                ((__hip_bfloat16*)pout)[(size_t)n * (HOUTP * WOUTP * CO)
                    + ((2 + r) * WOUTP + (2 + pw)) * CO + co] = __float2bfloat16(vm);
            }
        }
    }
}

// h (128, 5952 NCHW f32) @ fw1^T + fb1 -> h1 (128,32)
__global__ __launch_bounds__(64)
void fc1_kernel(const float* __restrict__ h,
                const float* __restrict__ fw1,
                const float* __restrict__ fb1,
                float* __restrict__ h1)
{
    const int n = blockIdx.x;
    const int j = blockIdx.y;
    const int lane = threadIdx.x;
    const float* hp = h   + (size_t)n * 5952;
    const float* wp = fw1 + (size_t)j * 5952;
    float s = 0.0f;
    for (int k = lane; k < 5952; k += 64) s = fmaf(hp[k], wp[k], s);
    #pragma unroll
    for (int off = 32; off > 0; off >>= 1) s += __shfl_down(s, off, 64);
    if (lane == 0) h1[n * 32 + j] = s + fb1[j];
}

__global__ __launch_bounds__(64)
void fc2_mean_kernel(const float* __restrict__ h1,
                     const float* __restrict__ fw2,
                     const float* __restrict__ fb2,
                     float* __restrict__ out)
{
    const int t = threadIdx.x;
    if (t >= 32) return;
    const int b = t >> 1, c = t & 1;
    float s = 0.0f;
    for (int l = 0; l < 8; ++l) {
        const float* hp = h1 + (size_t)(b * 8 + l) * 32;
        #pragma unroll
        for (int j = 0; j < 32; ++j) s = fmaf(hp[j], fw2[c * 32 + j], s);
    }
    out[t] = fmaf(s, 0.125f, fb2[c]);
}

extern "C" void kernel_launch(void* const* d_in, const int* in_sizes, int n_in,
                              void* d_out, int out_size, void* d_ws, size_t ws_size,
                              hipStream_t stream)
{
    const float* x   = (const float*)d_in[0];
    const float* w1  = (const float*)d_in[1];
    const float* b1  = (const float*)d_in[2];
    const float* g1  = (const float*)d_in[3];
    const float* be1 = (const float*)d_in[4];
    const float* m1  = (const float*)d_in[5];
    const float* v1  = (const float*)d_in[6];
    const float* w2  = (const float*)d_in[7];
    const float* b2  = (const float*)d_in[8];
    const float* g2  = (const float*)d_in[9];
    const float* be2 = (const float*)d_in[10];
    const float* m2  = (const float*)d_in[11];
    const float* v2  = (const float*)d_in[12];
    const float* w3  = (const float*)d_in[13];
    const float* b3  = (const float*)d_in[14];
    const float* g3  = (const float*)d_in[15];
    const float* be3 = (const float*)d_in[16];
    const float* m3  = (const float*)d_in[17];
    const float* v3  = (const float*)d_in[18];
    const float* w4  = (const float*)d_in[19];
    const float* b4  = (const float*)d_in[20];
    const float* g4  = (const float*)d_in[21];
    const float* be4 = (const float*)d_in[22];
    const float* m4  = (const float*)d_in[23];
    const float* v4  = (const float*)d_in[24];
    const float* fw1 = (const float*)d_in[25];
    const float* fb1 = (const float*)d_in[26];
    const float* fw2 = (const float*)d_in[27];
    const float* fb2 = (const float*)d_in[28];

    char* ws = (char*)d_ws;
    __hip_bfloat16* p1  = (__hip_bfloat16*)(ws + P1_OFF);
    __hip_bfloat16* p2  = (__hip_bfloat16*)(ws + P2_OFF);
    __hip_bfloat16* p3  = (__hip_bfloat16*)(ws + P3_OFF);
    float*          l4  = (float*)(ws + L4_OFF);
    float*          h1  = (float*)(ws + H1_OFF);
    __hip_bfloat16* wt2 = (__hip_bfloat16*)(ws + WT2_OFF);
    __hip_bfloat16* wt3 = (__hip_bfloat16*)(ws + WT3_OFF);
    __hip_bfloat16* wt4 = (__hip_bfloat16*)(ws + WT4_OFF);
    float*          ss2 = (float*)(ws + SS2_OFF);
    float*          ss3 = (float*)(ws + SS3_OFF);
    float*          ss4 = (float*)(ws + SS4_OFF);

    // zero only pad/halo regions (interiors are fully overwritten)
    pad_zero<54, 260, 16, 50, 250><<<dim3(7020), 256, 0, stream>>>(p1);
    pad_zero<29, 136, 32, 25, 125><<<dim3(1858), 256, 0, stream>>>(p2);
    pad_zero<16,  68, 64, 12,  62><<<dim3(544),  256, 0, stream>>>(p3);

    wtrans_kernel<<<dim3(50),  256, 0, stream>>>(w2, wt2, 32, 16);
    wtrans_kernel<<<dim3(200), 256, 0, stream>>>(w3, wt3, 64, 32);
    wtrans_kernel<<<dim3(200), 256, 0, stream>>>(w4, wt4, 32, 64);
    scsh_kernel<<<1, 64, 0, stream>>>(b2, g2, be2, m2, v2, ss2, 32);
    scsh_kernel<<<1, 64, 0, stream>>>(b3, g3, be3, m3, v3, ss3, 64);
    scsh_kernel<<<1, 64, 0, stream>>>(b4, g4, be4, m4, v4, ss4, 32);

    conv1_kernel<<<dim3(49, 128), 256, 0, stream>>>(x, w1, b1, g1, be1, m1, v1, p1);

    conv_mfma<16, 32, 54, 260, 29, 136, 25, 125, 8, 1, false>
        <<<dim3(128 * 25 * 8 / 4), 256, 0, stream>>>(p1, wt2, ss2, p2);
    conv_mfma<32, 64, 29, 136, 16, 68, 12, 62, 4, 2, false>
        <<<dim3(128 * 12 * 4 * 2 / 4), 256, 0, stream>>>(p2, wt3, ss3, p3);
    conv_mfma<64, 32, 16, 68, 0, 0, 6, 31, 2, 1, true>
        <<<dim3(128 * 6 * 2 / 4), 256, 0, stream>>>(p3, wt4, ss4, l4);

    fc1_kernel<<<dim3(128, 32), 64, 0, stream>>>(l4, fw1, fb1, h1);
    fc2_mean_kernel<<<1, 64, 0, stream>>>(h1, fw2, fb2, (float*)d_out);
}

// Round 5
// 470.748 us; speedup vs baseline: 8.1752x; 1.0652x over previous
//
#include <hip/hip_runtime.h>
#include <hip/hip_bf16.h>

#define EPSB 1e-5f

typedef short s16x8 __attribute__((ext_vector_type(8)));
typedef float f32x16 __attribute__((ext_vector_type(16)));

// ---------------- workspace layout (bytes) ----------------
//  p1: 128 x [54][260][16]  = 57,507,840 B   (conv1 out / conv2 in)
//  p2: 128 x [29][136][32]  = 32,309,248 B   (conv2 out / conv3 in)
//  p3: 128 x [16][68][64]   = 17,825,792 B   (conv3 out / conv4 in)
#define P1_OFF   0
#define P2_OFF   57507840
#define P3_OFF   89817088
#define PTOT     107642880
#define L4_OFF   107642880   // 128x32x6x31 f32 NCHW = 3,047,424 B
#define H1_OFF   110690304   // 128x32 f32
#define WT2_OFF  110706688   // [25][32][16] bf16
#define WT3_OFF  110732288   // [25][64][32] bf16
#define WT4_OFF  110834688   // [25][32][64] bf16
#define SS2_OFF  110937088   // 2*32 f32 (scale, shift)
#define SS3_OFF  110937344   // 2*64 f32
#define SS4_OFF  110937856   // 2*32 f32

__device__ __forceinline__ unsigned short bf16bits(float f) {
    __hip_bfloat16 h = __float2bfloat16(f);
    union { __hip_bfloat16 h; unsigned short u; } cv; cv.h = h; return cv.u;
}

// Zero only the pad/halo elements of a padded NHWC buffer.
template<int HP, int WP, int C, int IH, int IW>
__global__ __launch_bounds__(256)
void pad_zero(__hip_bfloat16* __restrict__ buf)
{
    const int idx = blockIdx.x * 256 + threadIdx.x;
    if (idx >= 128 * HP * WP) return;
    const int rc = idx % (HP * WP);
    const int row = rc / WP, col = rc % WP;
    const bool pad = (row < 2) | (row >= 2 + IH) | (col < 2) | (col >= 2 + IW);
    if (!pad) return;
    int4* p = reinterpret_cast<int4*>(buf + (size_t)idx * C);
    #pragma unroll
    for (int i = 0; i < C * 2 / 16; ++i) p[i] = int4{0, 0, 0, 0};
}

// Reorder conv weights (CO,CI,5,5) f32 -> [tap=kh*5+kw][CO][CI] bf16
__global__ __launch_bounds__(256)
void wtrans_kernel(const float* __restrict__ src, __hip_bfloat16* __restrict__ dst,
                   int CO, int CI)
{
    const int idx = blockIdx.x * 256 + threadIdx.x;
    if (idx >= CO * CI * 25) return;
    const int co  = idx / (CI * 25);
    const int rem = idx % (CI * 25);
    const int ci  = rem / 25;
    const int tap = rem % 25;
    dst[((size_t)tap * CO + co) * CI + ci] = __float2bfloat16(src[idx]);
}

// Per-channel BN fold: out[0..CO)=scale, out[CO..2CO)=shift
__global__ __launch_bounds__(64)
void scsh_kernel(const float* __restrict__ b, const float* __restrict__ g,
                 const float* __restrict__ be, const float* __restrict__ m,
                 const float* __restrict__ v, float* __restrict__ out, int CO)
{
    const int i = threadIdx.x;
    if (i < CO) {
        const float sc = g[i] * rsqrtf(v[i] + EPSB);
        out[i]      = sc;
        out[CO + i] = fmaf(b[i] - m[i], sc, be[i]);
    }
}

// conv1: CI=1, fp32 direct. One thread = one pooled pixel, all 16 channels.
// Window pinned in VGPRs via asm to stop the compiler sinking the loads
// into the co-loop (round-4 counters: VGPR=32 -> 16x window reload).
__global__ __launch_bounds__(256, 4)
void conv1_kernel(const float* __restrict__ x,
                  const float* __restrict__ wgt,   // (16,1,5,5)
                  const float* __restrict__ bias,
                  const float* __restrict__ g,
                  const float* __restrict__ be,
                  const float* __restrict__ m,
                  const float* __restrict__ v,
                  __hip_bfloat16* __restrict__ p1)
{
    const int n   = blockIdx.y;            // 0..127 (b*8 + l)
    const int idx = blockIdx.x * 256 + threadIdx.x;
    if (idx >= 50 * 250) return;
    const int ph = idx / 250, pw = idx % 250;

    const int b = n >> 3, l = n & 7;
    const float* ib = x + (size_t)b * 400000 + l * 500;

    const int h0  = 2 * ph - 2;
    const int w0c = 2 * pw - 2;
    float win[6][6];
    #pragma unroll
    for (int r = 0; r < 6; ++r) {
        const int hh = h0 + r;
        const bool vr = (hh >= 0) & (hh < 100);
        #pragma unroll
        for (int c = 0; c < 6; ++c) {
            const int ww = w0c + c;
            const bool ok = vr & (ww >= 0) & (ww < 500);
            win[r][c] = ok ? ib[hh * 4000 + ww] : 0.0f;
        }
    }
    // pin the 36 window values in registers
    #pragma unroll
    for (int r = 0; r < 6; ++r)
        #pragma unroll
        for (int c = 0; c < 6; ++c)
            asm volatile("" : "+v"(win[r][c]));

    float o[16];
    #pragma unroll
    for (int co = 0; co < 16; ++co) {
        float a0 = 0.f, a1 = 0.f, a2 = 0.f, a3 = 0.f;
        #pragma unroll
        for (int kh = 0; kh < 5; ++kh) {
            #pragma unroll
            for (int kw = 0; kw < 5; ++kw) {
                const float w = wgt[co * 25 + kh * 5 + kw];
                a0 = fmaf(w, win[kh  ][kw  ], a0);
                a1 = fmaf(w, win[kh  ][kw+1], a1);
                a2 = fmaf(w, win[kh+1][kw  ], a2);
                a3 = fmaf(w, win[kh+1][kw+1], a3);
            }
        }
        const float sc = g[co] * rsqrtf(v[co] + EPSB);
        const float sh = fmaf(bias[co] - m[co], sc, be[co]);
        #define RA(a) fmaxf(fmaf((a), sc, sh), 0.0f)
        o[co] = fmaxf(fmaxf(RA(a0), RA(a1)), fmaxf(RA(a2), RA(a3)));
        #undef RA
    }

    int4 v0, v1;
    v0.x = bf16bits(o[0])  | (bf16bits(o[1])  << 16);
    v0.y = bf16bits(o[2])  | (bf16bits(o[3])  << 16);
    v0.z = bf16bits(o[4])  | (bf16bits(o[5])  << 16);
    v0.w = bf16bits(o[6])  | (bf16bits(o[7])  << 16);
    v1.x = bf16bits(o[8])  | (bf16bits(o[9])  << 16);
    v1.y = bf16bits(o[10]) | (bf16bits(o[11]) << 16);
    v1.z = bf16bits(o[12]) | (bf16bits(o[13]) << 16);
    v1.w = bf16bits(o[14]) | (bf16bits(o[15]) << 16);
    int4* dst = reinterpret_cast<int4*>(
        p1 + (size_t)n * (54 * 260 * 16) + ((2 + ph) * 260 + (2 + pw)) * 16);
    dst[0] = v0;
    dst[1] = v1;
}

// Generic MFMA conv+BN+ReLU+pool.
// RPW = pool rows per wave (1 or 2). For RPW=2 a wave computes 4 conv rows,
// so 2*RPW+4 = 8 B-row fragments feed 20 MFMAs per (kw,s) step.
// Row index is clamped to HINP-1 (bottom pad rows are zero; results for
// out-of-range pool rows are discarded at the store).
template<int CI, int CO, int HINP, int WINP, int HOUTP, int WOUTP,
         int PH, int PW, int NT, int NCOT, int RPW, bool NCHW_OUT>
__global__ __launch_bounds__(256)
void conv_mfma(const __hip_bfloat16* __restrict__ pin,
               const __hip_bfloat16* __restrict__ wq,
               const float* __restrict__ scsh,
               void* __restrict__ pout)
{
    constexpr int R = (PH + RPW - 1) / RPW;   // waves per (n, wt, cot)
    constexpr int NROW = 2 * RPW + 4;         // B rows staged per step
    const int lane = threadIdx.x & 63;
    int t = blockIdx.x * 4 + (threadIdx.x >> 6);
    const int cot = t % NCOT; t /= NCOT;
    const int wt  = t % NT;   t /= NT;
    const int r   = t % R;    t /= R;
    const int n   = t;
    if (n >= 128) return;

    const int lw = lane & 31, loct = lane >> 5;
    const int co0 = cot * 32;
    const int w0  = wt * 32;

    const __hip_bfloat16* bbase = pin + (size_t)n * (HINP * WINP * CI)
                                + (w0 + lw) * CI + loct * 8;
    const __hip_bfloat16* abase = wq + (co0 + lw) * CI + loct * 8;

    f32x16 acc[2 * RPW];
    #pragma unroll
    for (int q = 0; q < 2 * RPW; ++q) acc[q] = (f32x16){};

    #pragma unroll
    for (int kw = 0; kw < 5; ++kw) {
        #pragma unroll
        for (int s = 0; s < CI / 16; ++s) {
            s16x8 bfr[NROW];
            #pragma unroll
            for (int j = 0; j < NROW; ++j) {
                const int row = (2 * RPW * r + j < HINP) ? (2 * RPW * r + j) : (HINP - 1);
                bfr[j] = *reinterpret_cast<const s16x8*>(bbase + (row * WINP + kw) * CI + s * 16);
            }
            #pragma unroll
            for (int kh = 0; kh < 5; ++kh) {
                const s16x8 a = *reinterpret_cast<const s16x8*>(
                    abase + (size_t)((kh * 5 + kw) * CO) * CI + s * 16);
                #pragma unroll
                for (int q = 0; q < 2 * RPW; ++q)
                    acc[q] = __builtin_amdgcn_mfma_f32_32x32x16_bf16(a, bfr[kh + q], acc[q], 0, 0, 0);
            }
        }
    }

    const int pw = wt * 16 + (lw >> 1);
    const bool act = ((lane & 1) == 0) && (pw < PW);
    #pragma unroll
    for (int p = 0; p < RPW; ++p) {
        const int pr = RPW * r + p;
        const bool rok = (pr < PH);
        #pragma unroll
        for (int reg = 0; reg < 16; ++reg) {
            const int co = co0 + (reg & 3) + 8 * (reg >> 2) + 4 * loct;
            const float sc = scsh[co], sh = scsh[CO + co];
            const float v0 = fmaxf(fmaf(acc[2 * p    ][reg], sc, sh), 0.0f);
            const float v1 = fmaxf(fmaf(acc[2 * p + 1][reg], sc, sh), 0.0f);
            float vm = fmaxf(v0, v1);
            vm = fmaxf(vm, __shfl_xor(vm, 1, 64));
            if (act && rok) {
                if (NCHW_OUT) {
                    ((float*)pout)[(((size_t)n * CO + co) * PH + pr) * PW + pw] = vm;
                } else {
                    ((__hip_bfloat16*)pout)[(size_t)n * (HOUTP * WOUTP * CO)
                        + ((2 + pr) * WOUTP + (2 + pw)) * CO + co] = __float2bfloat16(vm);
                }
            }
        }
    }
}

// h (128, 5952 NCHW f32) @ fw1^T + fb1 -> h1 (128,32)
__global__ __launch_bounds__(64)
void fc1_kernel(const float* __restrict__ h,
                const float* __restrict__ fw1,
                const float* __restrict__ fb1,
                float* __restrict__ h1)
{
    const int n = blockIdx.x;
    const int j = blockIdx.y;
    const int lane = threadIdx.x;
    const float* hp = h   + (size_t)n * 5952;
    const float* wp = fw1 + (size_t)j * 5952;
    float s = 0.0f;
    for (int k = lane; k < 5952; k += 64) s = fmaf(hp[k], wp[k], s);
    #pragma unroll
    for (int off = 32; off > 0; off >>= 1) s += __shfl_down(s, off, 64);
    if (lane == 0) h1[n * 32 + j] = s + fb1[j];
}

__global__ __launch_bounds__(64)
void fc2_mean_kernel(const float* __restrict__ h1,
                     const float* __restrict__ fw2,
                     const float* __restrict__ fb2,
                     float* __restrict__ out)
{
    const int t = threadIdx.x;
    if (t >= 32) return;
    const int b = t >> 1, c = t & 1;
    float s = 0.0f;
    for (int l = 0; l < 8; ++l) {
        const float* hp = h1 + (size_t)(b * 8 + l) * 32;
        #pragma unroll
        for (int j = 0; j < 32; ++j) s = fmaf(hp[j], fw2[c * 32 + j], s);
    }
    out[t] = fmaf(s, 0.125f, fb2[c]);
}

extern "C" void kernel_launch(void* const* d_in, const int* in_sizes, int n_in,
                              void* d_out, int out_size, void* d_ws, size_t ws_size,
                              hipStream_t stream)
{
    const float* x   = (const float*)d_in[0];
    const float* w1  = (const float*)d_in[1];
    const float* b1  = (const float*)d_in[2];
    const float* g1  = (const float*)d_in[3];
    const float* be1 = (const float*)d_in[4];
    const float* m1  = (const float*)d_in[5];
    const float* v1  = (const float*)d_in[6];
    const float* w2  = (const float*)d_in[7];
    const float* b2  = (const float*)d_in[8];
    const float* g2  = (const float*)d_in[9];
    const float* be2 = (const float*)d_in[10];
    const float* m2  = (const float*)d_in[11];
    const float* v2  = (const float*)d_in[12];
    const float* w3  = (const float*)d_in[13];
    const float* b3  = (const float*)d_in[14];
    const float* g3  = (const float*)d_in[15];
    const float* be3 = (const float*)d_in[16];
    const float* m3  = (const float*)d_in[17];
    const float* v3  = (const float*)d_in[18];
    const float* w4  = (const float*)d_in[19];
    const float* b4  = (const float*)d_in[20];
    const float* g4  = (const float*)d_in[21];
    const float* be4 = (const float*)d_in[22];
    const float* m4  = (const float*)d_in[23];
    const float* v4  = (const float*)d_in[24];
    const float* fw1 = (const float*)d_in[25];
    const float* fb1 = (const float*)d_in[26];
    const float* fw2 = (const float*)d_in[27];
    const float* fb2 = (const float*)d_in[28];

    char* ws = (char*)d_ws;
    __hip_bfloat16* p1  = (__hip_bfloat16*)(ws + P1_OFF);
    __hip_bfloat16* p2  = (__hip_bfloat16*)(ws + P2_OFF);
    __hip_bfloat16* p3  = (__hip_bfloat16*)(ws + P3_OFF);
    float*          l4  = (float*)(ws + L4_OFF);
    float*          h1  = (float*)(ws + H1_OFF);
    __hip_bfloat16* wt2 = (__hip_bfloat16*)(ws + WT2_OFF);
    __hip_bfloat16* wt3 = (__hip_bfloat16*)(ws + WT3_OFF);
    __hip_bfloat16* wt4 = (__hip_bfloat16*)(ws + WT4_OFF);
    float*          ss2 = (float*)(ws + SS2_OFF);
    float*          ss3 = (float*)(ws + SS3_OFF);
    float*          ss4 = (float*)(ws + SS4_OFF);

    // zero only pad/halo regions (interiors are fully overwritten)
    pad_zero<54, 260, 16, 50, 250><<<dim3(7020), 256, 0, stream>>>(p1);
    pad_zero<29, 136, 32, 25, 125><<<dim3(1858), 256, 0, stream>>>(p2);
    pad_zero<16,  68, 64, 12,  62><<<dim3(544),  256, 0, stream>>>(p3);

    wtrans_kernel<<<dim3(50),  256, 0, stream>>>(w2, wt2, 32, 16);
    wtrans_kernel<<<dim3(200), 256, 0, stream>>>(w3, wt3, 64, 32);
    wtrans_kernel<<<dim3(200), 256, 0, stream>>>(w4, wt4, 32, 64);
    scsh_kernel<<<1, 64, 0, stream>>>(b2, g2, be2, m2, v2, ss2, 32);
    scsh_kernel<<<1, 64, 0, stream>>>(b3, g3, be3, m3, v3, ss3, 64);
    scsh_kernel<<<1, 64, 0, stream>>>(b4, g4, be4, m4, v4, ss4, 32);

    conv1_kernel<<<dim3(49, 128), 256, 0, stream>>>(x, w1, b1, g1, be1, m1, v1, p1);

    // conv2: RPW=2, R=13 (pool row 24 handled by clamp+store-guard)
    conv_mfma<16, 32, 54, 260, 29, 136, 25, 125, 8, 1, 2, false>
        <<<dim3(128 * 13 * 8 / 4), 256, 0, stream>>>(p1, wt2, ss2, p2);
    // conv3: RPW=2, R=6
    conv_mfma<32, 64, 29, 136, 16, 68, 12, 62, 4, 2, 2, false>
        <<<dim3(128 * 6 * 4 * 2 / 4), 256, 0, stream>>>(p2, wt3, ss3, p3);
    // conv4: RPW=1 (keep grid width), NCHW f32 out
    conv_mfma<64, 32, 16, 68, 0, 0, 6, 31, 2, 1, 1, true>
        <<<dim3(128 * 6 * 2 / 4), 256, 0, stream>>>(p3, wt4, ss4, l4);

    fc1_kernel<<<dim3(128, 32), 64, 0, stream>>>(l4, fw1, fb1, h1);
    fc2_mean_kernel<<<1, 64, 0, stream>>>(h1, fw2, fb2, (float*)d_out);
}

// Round 6
// 456.573 us; speedup vs baseline: 8.4290x; 1.0310x over previous
//
#include <hip/hip_runtime.h>
#include <hip/hip_bf16.h>

#define EPSB 1e-5f

typedef short s16x8 __attribute__((ext_vector_type(8)));
typedef float f32x16 __attribute__((ext_vector_type(16)));

// ---------------- workspace layout (bytes) ----------------
//  p1: 128 x [54][260][16]  = 57,507,840 B   (conv1 out / conv2 in)
//  p2: 128 x [29][136][32]  = 32,309,248 B   (conv2 out / conv3 in)
//  p3: 128 x [16][68][64]   = 17,825,792 B   (conv3 out / conv4 in)
#define P1_OFF   0
#define P2_OFF   57507840
#define P3_OFF   89817088
#define L4_OFF   107642880   // 128x32x6x31 f32 NCHW = 3,047,424 B
#define H1_OFF   110690304   // 128x32 f32
#define WT2_OFF  110706688   // [25][32][16] bf16
#define WT3_OFF  110732288   // [25][64][32] bf16
#define WT4_OFF  110834688   // [25][32][64] bf16
#define SS2_OFF  110937088   // 2*32 f32 (scale, shift)
#define SS3_OFF  110937344   // 2*64 f32
#define SS4_OFF  110937856   // 2*32 f32

__device__ __forceinline__ unsigned short bf16bits(float f) {
    __hip_bfloat16 h = __float2bfloat16(f);
    union { __hip_bfloat16 h; unsigned short u; } cv; cv.h = h; return cv.u;
}

// ---- prep bodies (merged into one kernel: 9 launches -> 1) ----

template<int HP, int WP, int C, int IH, int IW>
__device__ __forceinline__ void pad_body(__hip_bfloat16* __restrict__ buf, int idx)
{
    if (idx >= 128 * HP * WP) return;
    const int rc = idx % (HP * WP);
    const int row = rc / WP, col = rc % WP;
    const bool pad = (row < 2) | (row >= 2 + IH) | (col < 2) | (col >= 2 + IW);
    if (!pad) return;
    int4* p = reinterpret_cast<int4*>(buf + (size_t)idx * C);
    #pragma unroll
    for (int i = 0; i < C * 2 / 16; ++i) p[i] = int4{0, 0, 0, 0};
}

__device__ __forceinline__ void wtrans_body(const float* __restrict__ src,
                                            __hip_bfloat16* __restrict__ dst,
                                            int CO, int CI, int idx)
{
    if (idx >= CO * CI * 25) return;
    const int co  = idx / (CI * 25);
    const int rem = idx % (CI * 25);
    const int ci  = rem / 25;
    const int tap = rem % 25;
    dst[((size_t)tap * CO + co) * CI + ci] = __float2bfloat16(src[idx]);
}

__device__ __forceinline__ void scsh_body(const float* __restrict__ b,
                                          const float* __restrict__ g,
                                          const float* __restrict__ be,
                                          const float* __restrict__ m,
                                          const float* __restrict__ v,
                                          float* __restrict__ out, int CO, int i)
{
    if (i < CO) {
        const float sc = g[i] * rsqrtf(v[i] + EPSB);
        out[i]      = sc;
        out[CO + i] = fmaf(b[i] - m[i], sc, be[i]);
    }
}

// block ranges: pad1 [0,7020) pad2 [7020,8992) pad3 [8992,9536)
// wt2 [9536,9586) wt3 [9586,9786) wt4 [9786,9986) scsh [9986,9989)
__global__ __launch_bounds__(256)
void prep_kernel(__hip_bfloat16* p1, __hip_bfloat16* p2, __hip_bfloat16* p3,
                 const float* w2, __hip_bfloat16* wt2,
                 const float* w3, __hip_bfloat16* wt3,
                 const float* w4, __hip_bfloat16* wt4,
                 const float* b2, const float* g2, const float* be2,
                 const float* m2, const float* v2, float* ss2,
                 const float* b3, const float* g3, const float* be3,
                 const float* m3, const float* v3, float* ss3,
                 const float* b4, const float* g4, const float* be4,
                 const float* m4, const float* v4, float* ss4)
{
    const int bid = blockIdx.x;
    const int tid = threadIdx.x;
    if      (bid < 7020) pad_body<54, 260, 16, 50, 250>(p1, bid * 256 + tid);
    else if (bid < 8992) pad_body<29, 136, 32, 25, 125>(p2, (bid - 7020) * 256 + tid);
    else if (bid < 9536) pad_body<16,  68, 64, 12,  62>(p3, (bid - 8992) * 256 + tid);
    else if (bid < 9586) wtrans_body(w2, wt2, 32, 16, (bid - 9536) * 256 + tid);
    else if (bid < 9786) wtrans_body(w3, wt3, 64, 32, (bid - 9586) * 256 + tid);
    else if (bid < 9986) wtrans_body(w4, wt4, 32, 64, (bid - 9786) * 256 + tid);
    else {
        const int which = bid - 9986;
        if      (which == 0) scsh_body(b2, g2, be2, m2, v2, ss2, 32, tid);
        else if (which == 1) scsh_body(b3, g3, be3, m3, v3, ss3, 64, tid);
        else                 scsh_body(b4, g4, be4, m4, v4, ss4, 32, tid);
    }
}

// conv1: CI=1, fp32 direct. One thread = one pooled pixel, all 16 channels.
// __launch_bounds__(256,1): min 1 wave/EU -> VGPR budget 512, so the
// allocator has no reason to spill/reload the 36-value window (round-5
// counters: VGPR=32, ~2.9x VALU overhead from re-loads).
__global__ __launch_bounds__(256, 1)
void conv1_kernel(const float* __restrict__ x,
                  const float* __restrict__ wgt,   // (16,1,5,5)
                  const float* __restrict__ bias,
                  const float* __restrict__ g,
                  const float* __restrict__ be,
                  const float* __restrict__ m,
                  const float* __restrict__ v,
                  __hip_bfloat16* __restrict__ p1)
{
    const int n   = blockIdx.y;            // 0..127 (b*8 + l)
    const int idx = blockIdx.x * 256 + threadIdx.x;
    if (idx >= 50 * 250) return;
    const int ph = idx / 250, pw = idx % 250;

    const int b = n >> 3, l = n & 7;
    const float* ib = x + (size_t)b * 400000 + l * 500;

    const int h0  = 2 * ph - 2;
    const int w0c = 2 * pw - 2;
    float win[6][6];
    #pragma unroll
    for (int r = 0; r < 6; ++r) {
        const int hh = h0 + r;
        const bool vr = (hh >= 0) & (hh < 100);
        #pragma unroll
        for (int c = 0; c < 6; ++c) {
            const int ww = w0c + c;
            const bool ok = vr & (ww >= 0) & (ww < 500);
            win[r][c] = ok ? ib[hh * 4000 + ww] : 0.0f;
        }
    }
    // pin the 36 window values in registers before the channel loop
    #pragma unroll
    for (int r = 0; r < 6; ++r)
        #pragma unroll
        for (int c = 0; c < 6; ++c)
            asm volatile("" : "+v"(win[r][c]));

    // process channels in pairs, packing results immediately (keeps the
    // live set ~55 regs: 36 win + <=8 packed + 4 accs)
    int packed[8];
    #pragma unroll
    for (int cp = 0; cp < 8; ++cp) {
        unsigned short h2[2];
        #pragma unroll
        for (int sub = 0; sub < 2; ++sub) {
            const int co = 2 * cp + sub;
            float a0 = 0.f, a1 = 0.f, a2 = 0.f, a3 = 0.f;
            #pragma unroll
            for (int kh = 0; kh < 5; ++kh) {
                #pragma unroll
                for (int kw = 0; kw < 5; ++kw) {
                    const float w = wgt[co * 25 + kh * 5 + kw];
                    a0 = fmaf(w, win[kh  ][kw  ], a0);
                    a1 = fmaf(w, win[kh  ][kw+1], a1);
                    a2 = fmaf(w, win[kh+1][kw  ], a2);
                    a3 = fmaf(w, win[kh+1][kw+1], a3);
                }
            }
            const float sc = g[co] * rsqrtf(v[co] + EPSB);
            const float sh = fmaf(bias[co] - m[co], sc, be[co]);
            #define RA(a) fmaxf(fmaf((a), sc, sh), 0.0f)
            h2[sub] = bf16bits(fmaxf(fmaxf(RA(a0), RA(a1)), fmaxf(RA(a2), RA(a3))));
            #undef RA
        }
        packed[cp] = h2[0] | (h2[1] << 16);
    }

    int4* dst = reinterpret_cast<int4*>(
        p1 + (size_t)n * (54 * 260 * 16) + ((2 + ph) * 260 + (2 + pw)) * 16);
    dst[0] = int4{packed[0], packed[1], packed[2], packed[3]};
    dst[1] = int4{packed[4], packed[5], packed[6], packed[7]};
}

// Generic MFMA conv+BN+ReLU+pool (unchanged from round 5).
template<int CI, int CO, int HINP, int WINP, int HOUTP, int WOUTP,
         int PH, int PW, int NT, int NCOT, int RPW, bool NCHW_OUT>
__global__ __launch_bounds__(256)
void conv_mfma(const __hip_bfloat16* __restrict__ pin,
               const __hip_bfloat16* __restrict__ wq,
               const float* __restrict__ scsh,
               void* __restrict__ pout)
{
    constexpr int R = (PH + RPW - 1) / RPW;   // waves per (n, wt, cot)
    constexpr int NROW = 2 * RPW + 4;         // B rows staged per step
    const int lane = threadIdx.x & 63;
    int t = blockIdx.x * 4 + (threadIdx.x >> 6);
    const int cot = t % NCOT; t /= NCOT;
    const int wt  = t % NT;   t /= NT;
    const int r   = t % R;    t /= R;
    const int n   = t;
    if (n >= 128) return;

    const int lw = lane & 31, loct = lane >> 5;
    const int co0 = cot * 32;
    const int w0  = wt * 32;

    const __hip_bfloat16* bbase = pin + (size_t)n * (HINP * WINP * CI)
                                + (w0 + lw) * CI + loct * 8;
    const __hip_bfloat16* abase = wq + (co0 + lw) * CI + loct * 8;

    f32x16 acc[2 * RPW];
    #pragma unroll
    for (int q = 0; q < 2 * RPW; ++q) acc[q] = (f32x16){};

    #pragma unroll
    for (int kw = 0; kw < 5; ++kw) {
        #pragma unroll
        for (int s = 0; s < CI / 16; ++s) {
            s16x8 bfr[NROW];
            #pragma unroll
            for (int j = 0; j < NROW; ++j) {
                const int row = (2 * RPW * r + j < HINP) ? (2 * RPW * r + j) : (HINP - 1);
                bfr[j] = *reinterpret_cast<const s16x8*>(bbase + (row * WINP + kw) * CI + s * 16);
            }
            #pragma unroll
            for (int kh = 0; kh < 5; ++kh) {
                const s16x8 a = *reinterpret_cast<const s16x8*>(
                    abase + (size_t)((kh * 5 + kw) * CO) * CI + s * 16);
                #pragma unroll
                for (int q = 0; q < 2 * RPW; ++q)
                    acc[q] = __builtin_amdgcn_mfma_f32_32x32x16_bf16(a, bfr[kh + q], acc[q], 0, 0, 0);
            }
        }
    }

    const int pw = wt * 16 + (lw >> 1);
    const bool act = ((lane & 1) == 0) && (pw < PW);
    #pragma unroll
    for (int p = 0; p < RPW; ++p) {
        const int pr = RPW * r + p;
        const bool rok = (pr < PH);
        #pragma unroll
        for (int reg = 0; reg < 16; ++reg) {
            const int co = co0 + (reg & 3) + 8 * (reg >> 2) + 4 * loct;
            const float sc = scsh[co], sh = scsh[CO + co];
            const float v0 = fmaxf(fmaf(acc[2 * p    ][reg], sc, sh), 0.0f);
            const float v1 = fmaxf(fmaf(acc[2 * p + 1][reg], sc, sh), 0.0f);
            float vm = fmaxf(v0, v1);
            vm = fmaxf(vm, __shfl_xor(vm, 1, 64));
            if (act && rok) {
                if (NCHW_OUT) {
                    ((float*)pout)[(((size_t)n * CO + co) * PH + pr) * PW + pw] = vm;
                } else {
                    ((__hip_bfloat16*)pout)[(size_t)n * (HOUTP * WOUTP * CO)
                        + ((2 + pr) * WOUTP + (2 + pw)) * CO + co] = __float2bfloat16(vm);
                }
            }
        }
    }
}

// h (128, 5952 NCHW f32) @ fw1^T + fb1 -> h1 (128,32)
__global__ __launch_bounds__(64)
void fc1_kernel(const float* __restrict__ h,
                const float* __restrict__ fw1,
                const float* __restrict__ fb1,
                float* __restrict__ h1)
{
    const int n = blockIdx.x;
    const int j = blockIdx.y;
    const int lane = threadIdx.x;
    const float* hp = h   + (size_t)n * 5952;
    const float* wp = fw1 + (size_t)j * 5952;
    float s = 0.0f;
    for (int k = lane; k < 5952; k += 64) s = fmaf(hp[k], wp[k], s);
    #pragma unroll
    for (int off = 32; off > 0; off >>= 1) s += __shfl_down(s, off, 64);
    if (lane == 0) h1[n * 32 + j] = s + fb1[j];
}

__global__ __launch_bounds__(64)
void fc2_mean_kernel(const float* __restrict__ h1,
                     const float* __restrict__ fw2,
                     const float* __restrict__ fb2,
                     float* __restrict__ out)
{
    const int t = threadIdx.x;
    if (t >= 32) return;
    const int b = t >> 1, c = t & 1;
    float s = 0.0f;
    for (int l = 0; l < 8; ++l) {
        const float* hp = h1 + (size_t)(b * 8 + l) * 32;
        #pragma unroll
        for (int j = 0; j < 32; ++j) s = fmaf(hp[j], fw2[c * 32 + j], s);
    }
    out[t] = fmaf(s, 0.125f, fb2[c]);
}

extern "C" void kernel_launch(void* const* d_in, const int* in_sizes, int n_in,
                              void* d_out, int out_size, void* d_ws, size_t ws_size,
                              hipStream_t stream)
{
    const float* x   = (const float*)d_in[0];
    const float* w1  = (const float*)d_in[1];
    const float* b1  = (const float*)d_in[2];
    const float* g1  = (const float*)d_in[3];
    const float* be1 = (const float*)d_in[4];
    const float* m1  = (const float*)d_in[5];
    const float* v1  = (const float*)d_in[6];
    const float* w2  = (const float*)d_in[7];
    const float* b2  = (const float*)d_in[8];
    const float* g2  = (const float*)d_in[9];
    const float* be2 = (const float*)d_in[10];
    const float* m2  = (const float*)d_in[11];
    const float* v2  = (const float*)d_in[12];
    const float* w3  = (const float*)d_in[13];
    const float* b3  = (const float*)d_in[14];
    const float* g3  = (const float*)d_in[15];
    const float* be3 = (const float*)d_in[16];
    const float* m3  = (const float*)d_in[17];
    const float* v3  = (const float*)d_in[18];
    const float* w4  = (const float*)d_in[19];
    const float* b4  = (const float*)d_in[20];
    const float* g4  = (const float*)d_in[21];
    const float* be4 = (const float*)d_in[22];
    const float* m4  = (const float*)d_in[23];
    const float* v4  = (const float*)d_in[24];
    const float* fw1 = (const float*)d_in[25];
    const float* fb1 = (const float*)d_in[26];
    const float* fw2 = (const float*)d_in[27];
    const float* fb2 = (const float*)d_in[28];

    char* ws = (char*)d_ws;
    __hip_bfloat16* p1  = (__hip_bfloat16*)(ws + P1_OFF);
    __hip_bfloat16* p2  = (__hip_bfloat16*)(ws + P2_OFF);
    __hip_bfloat16* p3  = (__hip_bfloat16*)(ws + P3_OFF);
    float*          l4  = (float*)(ws + L4_OFF);
    float*          h1  = (float*)(ws + H1_OFF);
    __hip_bfloat16* wt2 = (__hip_bfloat16*)(ws + WT2_OFF);
    __hip_bfloat16* wt3 = (__hip_bfloat16*)(ws + WT3_OFF);
    __hip_bfloat16* wt4 = (__hip_bfloat16*)(ws + WT4_OFF);
    float*          ss2 = (float*)(ws + SS2_OFF);
    float*          ss3 = (float*)(ws + SS3_OFF);
    float*          ss4 = (float*)(ws + SS4_OFF);

    prep_kernel<<<dim3(9989), 256, 0, stream>>>(
        p1, p2, p3, w2, wt2, w3, wt3, w4, wt4,
        b2, g2, be2, m2, v2, ss2,
        b3, g3, be3, m3, v3, ss3,
        b4, g4, be4, m4, v4, ss4);

    conv1_kernel<<<dim3(49, 128), 256, 0, stream>>>(x, w1, b1, g1, be1, m1, v1, p1);

    // conv2: RPW=2, R=13 (pool row 24 handled by clamp+store-guard)
    conv_mfma<16, 32, 54, 260, 29, 136, 25, 125, 8, 1, 2, false>
        <<<dim3(128 * 13 * 8 / 4), 256, 0, stream>>>(p1, wt2, ss2, p2);
    // conv3: RPW=2, R=6
    conv_mfma<32, 64, 29, 136, 16, 68, 12, 62, 4, 2, 2, false>
        <<<dim3(128 * 6 * 4 * 2 / 4), 256, 0, stream>>>(p2, wt3, ss3, p3);
    // conv4: RPW=1, NCHW f32 out
    conv_mfma<64, 32, 16, 68, 0, 0, 6, 31, 2, 1, 1, true>
        <<<dim3(128 * 6 * 2 / 4), 256, 0, stream>>>(p3, wt4, ss4, l4);

    fc1_kernel<<<dim3(128, 32), 64, 0, stream>>>(l4, fw1, fb1, h1);
    fc2_mean_kernel<<<1, 64, 0, stream>>>(h1, fw2, fb2, (float*)d_out);
}